// Round 3
// baseline (257.201 us; speedup 1.0000x reference)
//
#include <hip/hip_runtime.h>

#define DIM   1024
#define HEADS 16
#define HDIM  64
#define BATCH 2
#define SEQ   2048
#define TOK   (BATCH*SEQ)   // 4096
#define MEG   1048576

typedef __bf16 bf16x8 __attribute__((ext_vector_type(8)));
typedef float  f32x4  __attribute__((ext_vector_type(4)));
typedef float  f32x16 __attribute__((ext_vector_type(16)));

__device__ __forceinline__ float b2f(ushort u) {
    union { unsigned int u32; float f; } x; x.u32 = ((unsigned int)u) << 16; return x.f;
}
__device__ __forceinline__ ushort f2b(float f) {
    union { float f; unsigned int u32; } x; x.f = f;
    unsigned int r = x.u32 + 0x7FFFu + ((x.u32 >> 16) & 1u);
    return (ushort)(r >> 16);
}
// async global->LDS, 16B per lane; lds dest = wave-uniform base + lane*16
__device__ __forceinline__ void gload_lds16(const ushort* g, void* l) {
    __builtin_amdgcn_global_load_lds((const __attribute__((address_space(1))) void*)g,
                                     (__attribute__((address_space(3))) void*)l, 16, 0, 0);
}
__device__ __forceinline__ float fexp2(float x) {   // 2^x, single v_exp_f32
    float r; asm("v_exp_f32 %0, %1" : "=v"(r) : "v"(x)); return r;
}
__device__ __forceinline__ unsigned int cvtpk_bf16(float lo, float hi) {
    unsigned int r; asm("v_cvt_pk_bf16_f32 %0, %1, %2" : "=v"(r) : "v"(lo), "v"(hi)); return r;
}
// swap a's upper 32 lanes with b's lower 32 lanes
__device__ __forceinline__ void plane32swap(unsigned int &a, unsigned int &b) {
    asm("v_permlane32_swap_b32 %0, %1" : "+v"(a), "+v"(b));
}
// pack 8 consecutive-key exp values (MFMA C-layout regs) into one A-frag
__device__ __forceinline__ bf16x8 pack8(float e0, float e1, float e2, float e3,
                                        float e4, float e5, float e6, float e7) {
    unsigned int a = cvtpk_bf16(e0, e1), b = cvtpk_bf16(e2, e3);
    unsigned int c = cvtpk_bf16(e4, e5), d = cvtpk_bf16(e6, e7);
    plane32swap(a, c); plane32swap(b, d);
    union { unsigned int u[4]; bf16x8 v; } r;
    r.u[0] = a; r.u[1] = b; r.u[2] = c; r.u[3] = d;
    return r.v;
}

// ------- tiled transpose + fp32->bf16 cast: src f32[R][Cc] -> dst bf16[Cc][R]
__global__ void transpose_f2b_k(const float* __restrict__ src, ushort* __restrict__ dst,
                                int R, int Cc) {
    __shared__ ushort tile[32][33];
    int c0 = blockIdx.x * 32, r0 = blockIdx.y * 32;
    int tx = threadIdx.x, ty = threadIdx.y;   // 32 x 8
#pragma unroll
    for (int i = 0; i < 4; i++)
        tile[ty + 8 * i][tx] = f2b(src[(long)(r0 + ty + 8 * i) * Cc + c0 + tx]);
    __syncthreads();
#pragma unroll
    for (int i = 0; i < 4; i++)
        dst[(long)(c0 + ty + 8 * i) * R + r0 + tx] = tile[tx][ty + 8 * i];
}

// ------- LayerNorm: one block per token, fp32 in -> bf16 out -----------------
__global__ __launch_bounds__(256)
void ln_k(const float* __restrict__ x, const float* __restrict__ gamma,
          const float* __restrict__ beta, ushort* __restrict__ h) {
    __shared__ float red[8];
    int row = blockIdx.x, tid = threadIdx.x;
    const float* xr = x + (long)row * DIM;
    float4 xv = *(const float4*)(xr + tid * 4);
    float s1 = xv.x + xv.y + xv.z + xv.w;
    float s2 = xv.x * xv.x + xv.y * xv.y + xv.z * xv.z + xv.w * xv.w;
#pragma unroll
    for (int off = 32; off; off >>= 1) {
        s1 += __shfl_down(s1, off);
        s2 += __shfl_down(s2, off);
    }
    int wid = tid >> 6, lane = tid & 63;
    if (lane == 0) { red[wid * 2] = s1; red[wid * 2 + 1] = s2; }
    __syncthreads();
    s1 = red[0] + red[2] + red[4] + red[6];
    s2 = red[1] + red[3] + red[5] + red[7];
    float mu  = s1 * (1.0f / DIM);
    float var = s2 * (1.0f / DIM) - mu * mu;
    float rs  = rsqrtf(var + 1e-5f);
    float4 gv = *(const float4*)(gamma + tid * 4);
    float4 bv = *(const float4*)(beta + tid * 4);
    ushort4 ov;
    ov.x = f2b((xv.x - mu) * rs * gv.x + bv.x);
    ov.y = f2b((xv.y - mu) * rs * gv.y + bv.y);
    ov.z = f2b((xv.z - mu) * rs * gv.z + bv.z);
    ov.w = f2b((xv.w - mu) * rs * gv.w + bv.w);
    *(ushort4*)(h + (long)row * DIM + tid * 4) = ov;
}

// ------- QKV GEMM: 128x128 tile, BK=64, global_load_lds staging --------------
// Col-tiles < 2048: scatter q/k to [B,H,N,D] (q pre-scaled 1/8 * log2e so the
// attention softmax can use bare v_exp_f32 = 2^x).
// Col-tiles >= 2048 (pure V): LDS-transpose acc and write V^T [B,H][D][N].
__global__ __launch_bounds__(256, 3)
void gemm_qkv_k(const ushort* __restrict__ A, const ushort* __restrict__ Bt,
                ushort* __restrict__ qp, ushort* __restrict__ kp, ushort* __restrict__ vp) {
    __shared__ ushort smem[16384];   // As: [0,8192) Bs: [8192,16384); reused as T[128][128]
    int tid  = threadIdx.x;
    int wid  = tid >> 6, lane = tid & 63;
    int quad = lane >> 4, l16 = lane & 15;
    int wm = wid >> 1, wn = wid & 1;
    int rowbase = blockIdx.y * 128;
    int colbase = blockIdx.x * 128;

    f32x4 acc[4][4];
#pragma unroll
    for (int i = 0; i < 4; i++)
#pragma unroll
        for (int j = 0; j < 4; j++) acc[i][j] = (f32x4){0.f, 0.f, 0.f, 0.f};

    for (int k0 = 0; k0 < DIM; k0 += 64) {
#pragma unroll
        for (int p = 0; p < 2; p++) {
            int c = wid * 2 + p;
            int r = c * 16 + (lane >> 2);
            int ac = (lane & 3) * 8;
#pragma unroll
            for (int pnl = 0; pnl < 2; pnl++) {
                int cc = k0 + pnl * 32 + ac;
                gload_lds16(A  + (long)(rowbase + r) * DIM + cc,
                            &smem[pnl * 4096 + c * 16 * 32]);
                gload_lds16(Bt + (long)(colbase + r) * DIM + cc,
                            &smem[8192 + pnl * 4096 + c * 16 * 32]);
            }
        }
        __syncthreads();
#pragma unroll
        for (int pnl = 0; pnl < 2; pnl++) {
            bf16x8 fa[4], fb[4];
#pragma unroll
            for (int t = 0; t < 4; t++)
                fa[t] = *(const bf16x8*)(&smem[pnl * 4096 + (wm * 64 + t * 16 + l16) * 32 + quad * 8]);
#pragma unroll
            for (int t = 0; t < 4; t++)
                fb[t] = *(const bf16x8*)(&smem[8192 + pnl * 4096 + (wn * 64 + t * 16 + l16) * 32 + quad * 8]);
#pragma unroll
            for (int i = 0; i < 4; i++)
#pragma unroll
                for (int j = 0; j < 4; j++)
                    acc[i][j] = __builtin_amdgcn_mfma_f32_16x16x32_bf16(fa[i], fb[j], acc[i][j], 0, 0, 0);
        }
        __syncthreads();
    }

    if (colbase >= 2048) {
        // V block: acc -> T[col_local][row_local] -> coalesced V^T write
#pragma unroll
        for (int i = 0; i < 4; i++)
#pragma unroll
            for (int j = 0; j < 4; j++) {
                int cl = wn * 64 + j * 16 + l16;
                int rl = wm * 64 + i * 16 + quad * 4;
#pragma unroll
                for (int r = 0; r < 4; r++)
                    smem[cl * 128 + rl + r] = f2b(acc[i][j][r]);
            }
        __syncthreads();
        int b = rowbase >> 11, nnb = rowbase & 2047;
        int hbase = (colbase - 2048) >> 6;
#pragma unroll
        for (int i = 0; i < 8; i++) {
            int id = i * 256 + tid;           // 0..2047
            int cl = id >> 4;                 // local col 0..127
            int off = (id & 15) * 8;          // 0..120
            int hh = hbase + (cl >> 6), d = cl & 63;
            uint4 val = *(const uint4*)(&smem[cl * 128 + off]);
            *(uint4*)(vp + (((long)b * HEADS + hh) * HDIM + d) * SEQ + nnb + off) = val;
        }
    } else {
#pragma unroll
        for (int i = 0; i < 4; i++)
#pragma unroll
            for (int j = 0; j < 4; j++) {
                int m0  = rowbase + wm * 64 + i * 16 + quad * 4;
                int col = colbase + wn * 64 + j * 16 + l16;
                int part = col >> 10, rem = col & 1023;
                int head = rem >> 6, d = rem & 63;
                ushort* dst = (part == 0) ? qp : kp;
#pragma unroll
                for (int r = 0; r < 4; r++) {
                    float v = acc[i][j][r];
                    int mm = m0 + r;
                    int b = mm >> 11, nn = mm & 2047;
                    // q scale = 1/sqrt(64) * log2(e)  (softmax uses 2^x)
                    float sv = (part == 0) ? v * 0.18033688011f : v;
                    dst[((((long)b * HEADS + head) * SEQ + nn) << 6) + d] = f2b(sv);
                }
            }
    }
}

// ------- Proj GEMM: 128x64 tile, BK=64; grid 512 -----------------------------
__global__ __launch_bounds__(256, 3)
void gemm_proj_k(const ushort* __restrict__ A, const ushort* __restrict__ Bt,
                 const float* __restrict__ bias, const float* __restrict__ xres,
                 float* __restrict__ outp) {
    __shared__ ushort As[2][128][32];   // 16 KB
    __shared__ ushort Bs[2][64][32];    // 8 KB
    int tid  = threadIdx.x;
    int wid  = tid >> 6, lane = tid & 63;
    int quad = lane >> 4, l16 = lane & 15;
    int rowbase = blockIdx.y * 128;
    int colbase = blockIdx.x * 64;
    int arow = lane >> 2, acol = (lane & 3) * 8;

    f32x4 acc[2][4];
#pragma unroll
    for (int i = 0; i < 2; i++)
#pragma unroll
        for (int j = 0; j < 4; j++) acc[i][j] = (f32x4){0.f, 0.f, 0.f, 0.f};

    for (int k0 = 0; k0 < DIM; k0 += 64) {
#pragma unroll
        for (int p = 0; p < 2; p++) {
            int c = wid * 2 + p;
            int r = c * 16 + arow;
            int mm = rowbase + r;
            int bq = mm >> 11, nn = mm & 2047;
#pragma unroll
            for (int pnl = 0; pnl < 2; pnl++) {
                int cc = k0 + pnl * 32 + acol;
                int head = cc >> 6, d = cc & 63;
                gload_lds16(A + ((((long)bq * HEADS + head) * SEQ + nn) << 6) + d,
                            &As[pnl][c * 16][0]);
            }
        }
        {
            int r = wid * 16 + arow;
#pragma unroll
            for (int pnl = 0; pnl < 2; pnl++) {
                int cc = k0 + pnl * 32 + acol;
                gload_lds16(Bt + (long)(colbase + r) * DIM + cc, &Bs[pnl][wid * 16][0]);
            }
        }
        __syncthreads();
#pragma unroll
        for (int pnl = 0; pnl < 2; pnl++) {
            bf16x8 fa[2], fb[4];
#pragma unroll
            for (int t = 0; t < 2; t++)
                fa[t] = *(const bf16x8*)(&As[pnl][wid * 32 + t * 16 + l16][quad * 8]);
#pragma unroll
            for (int t = 0; t < 4; t++)
                fb[t] = *(const bf16x8*)(&Bs[pnl][t * 16 + l16][quad * 8]);
#pragma unroll
            for (int i = 0; i < 2; i++)
#pragma unroll
                for (int j = 0; j < 4; j++)
                    acc[i][j] = __builtin_amdgcn_mfma_f32_16x16x32_bf16(fa[i], fb[j], acc[i][j], 0, 0, 0);
        }
        __syncthreads();
    }

#pragma unroll
    for (int i = 0; i < 2; i++)
#pragma unroll
        for (int j = 0; j < 4; j++) {
            int m0  = rowbase + wid * 32 + i * 16 + quad * 4;
            int col = colbase + j * 16 + l16;
#pragma unroll
            for (int r = 0; r < 4; r++) {
                int mm = m0 + r;
                outp[(long)mm * DIM + col] = acc[i][j][r] + bias[col] + xres[(long)mm * DIM + col];
            }
        }
}

// ------- flash attention: LDS-free, barrier-free, register double-buffer -----
// K+V per (b,h) = 512 KB -> L2-resident across the 16 q-blocks that share it
// (m169 lesson: don't LDS-stage L2-fit data). Each wave loads its MFMA A/B
// fragments straight from global:
//   K A-frag  (swapped QK^T, A=K[key][d]): lane(l31,hi) reads
//       K[kt + (half?32:0) + l31][ks*16 + hi*8 ..+8]      (16B per lane)
//   V B-frag  (PV, B=V[k][d] == V^T[d][k] rows): lane(l31,hi) reads
//       V^T[(half?32:0)+l31][kt + g*16 + hi*8 ..+8]
// Register-double-buffered one 64-key iteration ahead; no __syncthreads, no
// LDS -- waves free-run and decorrelate, filling each other's VALU phases.
__device__ __forceinline__ void load_kv(const ushort* kb0, const ushort* kb1,
                                        const ushort* vb0, const ushort* vb1, int kt,
                                        bf16x8 (&kf)[8], bf16x8 (&vf)[8]) {
#pragma unroll
    for (int g = 0; g < 4; g++) {
        kf[2*g]   = *(const bf16x8*)(kb0 + (long)kt * HDIM + g * 16);
        kf[2*g+1] = *(const bf16x8*)(kb1 + (long)kt * HDIM + g * 16);
        vf[2*g]   = *(const bf16x8*)(vb0 + kt + g * 16);
        vf[2*g+1] = *(const bf16x8*)(vb1 + kt + g * 16);
    }
}

__device__ __forceinline__ void attn_body(const bf16x8 (&kf)[8], const bf16x8 (&vf)[8],
                                          const bf16x8 (&qf)[4],
                                          f32x16 &o0, f32x16 &o1, f32x4 &lac) {
    // QK^T: two independent 4-chains (keys 0-31 / 32-63 of this block)
    f32x16 sc0 = {}, sc1 = {};
    __builtin_amdgcn_s_setprio(1);
#pragma unroll
    for (int ks = 0; ks < 4; ks++) {
        sc0 = __builtin_amdgcn_mfma_f32_32x32x16_bf16(kf[2*ks],   qf[ks], sc0, 0, 0, 0);
        sc1 = __builtin_amdgcn_mfma_f32_32x32x16_bf16(kf[2*ks+1], qf[ks], sc1, 0, 0, 0);
    }
    __builtin_amdgcn_s_setprio(0);

    // softmax numerators: 2^(sc) (log2e folded into q scale)
    float e0[16], e1[16];
#pragma unroll
    for (int r = 0; r < 16; r++) { e0[r] = fexp2(sc0[r]); e1[r] = fexp2(sc1[r]); }
#pragma unroll
    for (int r = 0; r < 4; r++)
        lac += (f32x4){e0[4*r], e0[4*r+1], e0[4*r+2], e0[4*r+3]}
             + (f32x4){e1[4*r], e1[4*r+1], e1[4*r+2], e1[4*r+3]};

    // P -> A-frags: 4 groups of 16 keys
    bf16x8 pa0 = pack8(e0[0], e0[1], e0[2],  e0[3],  e0[4],  e0[5],  e0[6],  e0[7]);
    bf16x8 pa1 = pack8(e0[8], e0[9], e0[10], e0[11], e0[12], e0[13], e0[14], e0[15]);
    bf16x8 pa2 = pack8(e1[0], e1[1], e1[2],  e1[3],  e1[4],  e1[5],  e1[6],  e1[7]);
    bf16x8 pa3 = pack8(e1[8], e1[9], e1[10], e1[11], e1[12], e1[13], e1[14], e1[15]);

    // PV: pa_g covers keys [16g,16g+16); vf[2g]=d 0-31 slice, vf[2g+1]=d 32-63
    __builtin_amdgcn_s_setprio(1);
    o0 = __builtin_amdgcn_mfma_f32_32x32x16_bf16(pa0, vf[0], o0, 0, 0, 0);
    o1 = __builtin_amdgcn_mfma_f32_32x32x16_bf16(pa0, vf[1], o1, 0, 0, 0);
    o0 = __builtin_amdgcn_mfma_f32_32x32x16_bf16(pa1, vf[2], o0, 0, 0, 0);
    o1 = __builtin_amdgcn_mfma_f32_32x32x16_bf16(pa1, vf[3], o1, 0, 0, 0);
    o0 = __builtin_amdgcn_mfma_f32_32x32x16_bf16(pa2, vf[4], o0, 0, 0, 0);
    o1 = __builtin_amdgcn_mfma_f32_32x32x16_bf16(pa2, vf[5], o1, 0, 0, 0);
    o0 = __builtin_amdgcn_mfma_f32_32x32x16_bf16(pa3, vf[6], o0, 0, 0, 0);
    o1 = __builtin_amdgcn_mfma_f32_32x32x16_bf16(pa3, vf[7], o1, 0, 0, 0);
    __builtin_amdgcn_s_setprio(0);
}

__global__ __launch_bounds__(256, 2)
void attn_k(ushort* qio, const ushort* __restrict__ kg,
            const ushort* __restrict__ vt) {
    int bh = blockIdx.y;
    int tid = threadIdx.x, wid = tid >> 6, lane = tid & 63;
    int l31 = lane & 31, hi = lane >> 5;
    ushort* qh = qio + (long)bh * SEQ * HDIM;
    const ushort* kh = kg + (long)bh * SEQ * HDIM;
    const ushort* vh = vt + (long)bh * HDIM * SEQ;

    int qrow0 = blockIdx.x * 128 + wid * 32;
    // Q B-frag: lane holds Q[q=l31][d = ks*16 + hi*8 + j]
    bf16x8 qf[4];
#pragma unroll
    for (int ks = 0; ks < 4; ks++)
        qf[ks] = *(const bf16x8*)(qh + (long)(qrow0 + l31) * HDIM + ks * 16 + hi * 8);

    f32x16 o0 = {}, o1 = {};                // PV acc: col=d=l31(+32)
    f32x4 lac = {0.f, 0.f, 0.f, 0.f};       // per-column (q) exp sums

    const ushort* kb0 = kh + (long)l31 * HDIM + hi * 8;
    const ushort* kb1 = kh + (long)(32 + l31) * HDIM + hi * 8;
    const ushort* vb0 = vh + (long)l31 * SEQ + hi * 8;
    const ushort* vb1 = vh + (long)(32 + l31) * SEQ + hi * 8;

    bf16x8 ka[8], va[8], kn[8], vn[8];
    load_kv(kb0, kb1, vb0, vb1, 0, ka, va);

    const int NIT = SEQ / 64;   // 32 (even)
    for (int it = 0; it < NIT - 2; it += 2) {
        load_kv(kb0, kb1, vb0, vb1, (it + 1) * 64, kn, vn);
        attn_body(ka, va, qf, o0, o1, lac);
        load_kv(kb0, kb1, vb0, vb1, (it + 2) * 64, ka, va);
        attn_body(kn, vn, qf, o0, o1, lac);
    }
    // tail pair (it = NIT-2)
    load_kv(kb0, kb1, vb0, vb1, (NIT - 1) * 64, kn, vn);
    attn_body(ka, va, qf, o0, o1, lac);
    attn_body(kn, vn, qf, o0, o1, lac);

    // denominators: column q sums split across lane pair (q, q+32)
    float t = lac[0] + lac[1] + lac[2] + lac[3];
    t += __shfl_xor(t, 32);
    float linv = 1.0f / t;          // valid in lanes q and q+32 for column q=l31
#pragma unroll
    for (int r = 0; r < 16; r++) {
        int qrow = (r & 3) + 8 * (r >> 2) + 4 * hi;
        float lr = __shfl(linv, qrow);        // lane qrow holds 1/sum for q=qrow
        long ro = (long)(qrow0 + qrow) * HDIM;
        qh[ro + l31]      = f2b(o0[r] * lr);
        qh[ro + 32 + l31] = f2b(o1[r] * lr);
    }
}

// ------- launch --------------------------------------------------------------
extern "C" void kernel_launch(void* const* d_in, const int* in_sizes, int n_in,
                              void* d_out, int out_size, void* d_ws, size_t ws_size,
                              hipStream_t stream) {
    const float* x      = (const float*)d_in[0];
    const float* w_qkv  = (const float*)d_in[1];
    const float* w_proj = (const float*)d_in[2];
    const float* b_proj = (const float*)d_in[3];
    const float* gamma  = (const float*)d_in[4];
    const float* beta   = (const float*)d_in[5];
    float* out = (float*)d_out;

    // workspace: 19M bf16 elements = 38 MB
    ushort* ws   = (ushort*)d_ws;
    ushort* h    = ws;                      // 4M: LN output
    ushort* wqt  = ws + (size_t)4 * MEG;    // 3M: w_qkv^T (bf16)
    ushort* qb   = ws + (size_t)7 * MEG;    // 4M: q (pre-scaled), then attn out (q-layout)
    ushort* kb   = ws + (size_t)11 * MEG;   // 4M: k, then w_proj^T
    ushort* vtb  = ws + (size_t)15 * MEG;   // 4M: V^T [B,H][D][N] (written by QKV epilogue)

    // 1) transpose+cast w_qkv f32[K][3N] -> bf16 [3N][K]
    transpose_f2b_k<<<dim3(3 * DIM / 32, DIM / 32), dim3(32, 8), 0, stream>>>(
        w_qkv, wqt, DIM, 3 * DIM);
    // 2) layernorm f32 -> bf16 h
    ln_k<<<dim3(TOK), dim3(256), 0, stream>>>(x, gamma, beta, h);
    // 3) qkv gemm: scatter q/k, V^T written directly (fused transpose)
    gemm_qkv_k<<<dim3(3 * DIM / 128, TOK / 128), dim3(256), 0, stream>>>(
        h, wqt, qb, kb, vtb);
    // 4) flash attention; output overwrites q buffer in q-layout
    attn_k<<<dim3(SEQ / 128, BATCH * HEADS), dim3(256), 0, stream>>>(qb, kb, vtb);
    // 5) transpose+cast w_proj into dead k slot
    transpose_f2b_k<<<dim3(DIM / 32, DIM / 32), dim3(32, 8), 0, stream>>>(
        w_proj, kb, DIM, DIM);
    // 6) proj gemm (+fp32 bias +fp32 residual) -> fp32 out, 128x64 tiles
    gemm_proj_k<<<dim3(DIM / 64, TOK / 128), dim3(256), 0, stream>>>(
        qb, kb, b_proj, x, out);
}

// Round 4
// 190.343 us; speedup vs baseline: 1.3513x; 1.3513x over previous
//
#include <hip/hip_runtime.h>

#define DIM   1024
#define HEADS 16
#define HDIM  64
#define BATCH 2
#define SEQ   2048
#define TOK   (BATCH*SEQ)   // 4096
#define MEG   1048576

typedef __bf16 bf16x8 __attribute__((ext_vector_type(8)));
typedef float  f32x4  __attribute__((ext_vector_type(4)));
typedef float  f32x16 __attribute__((ext_vector_type(16)));

__device__ __forceinline__ float b2f(ushort u) {
    union { unsigned int u32; float f; } x; x.u32 = ((unsigned int)u) << 16; return x.f;
}
__device__ __forceinline__ ushort f2b(float f) {
    union { float f; unsigned int u32; } x; x.f = f;
    unsigned int r = x.u32 + 0x7FFFu + ((x.u32 >> 16) & 1u);
    return (ushort)(r >> 16);
}
// async global->LDS, 16B per lane; lds dest = wave-uniform base + lane*16
__device__ __forceinline__ void gload_lds16(const ushort* g, void* l) {
    __builtin_amdgcn_global_load_lds((const __attribute__((address_space(1))) void*)g,
                                     (__attribute__((address_space(3))) void*)l, 16, 0, 0);
}
__device__ __forceinline__ float fexp2(float x) {   // 2^x, single v_exp_f32
    float r; asm("v_exp_f32 %0, %1" : "=v"(r) : "v"(x)); return r;
}
__device__ __forceinline__ unsigned int cvtpk_bf16(float lo, float hi) {
    unsigned int r; asm("v_cvt_pk_bf16_f32 %0, %1, %2" : "=v"(r) : "v"(lo), "v"(hi)); return r;
}
// swap a's upper 32 lanes with b's lower 32 lanes
__device__ __forceinline__ void plane32swap(unsigned int &a, unsigned int &b) {
    asm("v_permlane32_swap_b32 %0, %1" : "+v"(a), "+v"(b));
}
// pack 8 consecutive-key exp values (MFMA C-layout regs) into one A-frag
__device__ __forceinline__ bf16x8 pack8(float e0, float e1, float e2, float e3,
                                        float e4, float e5, float e6, float e7) {
    unsigned int a = cvtpk_bf16(e0, e1), b = cvtpk_bf16(e2, e3);
    unsigned int c = cvtpk_bf16(e4, e5), d = cvtpk_bf16(e6, e7);
    plane32swap(a, c); plane32swap(b, d);
    union { unsigned int u[4]; bf16x8 v; } r;
    r.u[0] = a; r.u[1] = b; r.u[2] = c; r.u[3] = d;
    return r.v;
}

// ------- tiled transpose + fp32->bf16 cast: src f32[R][Cc] -> dst bf16[Cc][R]
__global__ void transpose_f2b_k(const float* __restrict__ src, ushort* __restrict__ dst,
                                int R, int Cc) {
    __shared__ ushort tile[32][33];
    int c0 = blockIdx.x * 32, r0 = blockIdx.y * 32;
    int tx = threadIdx.x, ty = threadIdx.y;   // 32 x 8
#pragma unroll
    for (int i = 0; i < 4; i++)
        tile[ty + 8 * i][tx] = f2b(src[(long)(r0 + ty + 8 * i) * Cc + c0 + tx]);
    __syncthreads();
#pragma unroll
    for (int i = 0; i < 4; i++)
        dst[(long)(c0 + ty + 8 * i) * R + r0 + tx] = tile[tx][ty + 8 * i];
}

// ------- LayerNorm: one block per token, fp32 in -> bf16 out -----------------
__global__ __launch_bounds__(256)
void ln_k(const float* __restrict__ x, const float* __restrict__ gamma,
          const float* __restrict__ beta, ushort* __restrict__ h) {
    __shared__ float red[8];
    int row = blockIdx.x, tid = threadIdx.x;
    const float* xr = x + (long)row * DIM;
    float4 xv = *(const float4*)(xr + tid * 4);
    float s1 = xv.x + xv.y + xv.z + xv.w;
    float s2 = xv.x * xv.x + xv.y * xv.y + xv.z * xv.z + xv.w * xv.w;
#pragma unroll
    for (int off = 32; off; off >>= 1) {
        s1 += __shfl_down(s1, off);
        s2 += __shfl_down(s2, off);
    }
    int wid = tid >> 6, lane = tid & 63;
    if (lane == 0) { red[wid * 2] = s1; red[wid * 2 + 1] = s2; }
    __syncthreads();
    s1 = red[0] + red[2] + red[4] + red[6];
    s2 = red[1] + red[3] + red[5] + red[7];
    float mu  = s1 * (1.0f / DIM);
    float var = s2 * (1.0f / DIM) - mu * mu;
    float rs  = rsqrtf(var + 1e-5f);
    float4 gv = *(const float4*)(gamma + tid * 4);
    float4 bv = *(const float4*)(beta + tid * 4);
    ushort4 ov;
    ov.x = f2b((xv.x - mu) * rs * gv.x + bv.x);
    ov.y = f2b((xv.y - mu) * rs * gv.y + bv.y);
    ov.z = f2b((xv.z - mu) * rs * gv.z + bv.z);
    ov.w = f2b((xv.w - mu) * rs * gv.w + bv.w);
    *(ushort4*)(h + (long)row * DIM + tid * 4) = ov;
}

// ------- QKV GEMM: 128x128 tile, BK=64, global_load_lds staging --------------
// Col-tiles < 2048: scatter q/k to [B,H,N,D] (q pre-scaled 1/8 * log2e so the
// attention softmax can use bare v_exp_f32 = 2^x).
// Col-tiles >= 2048 (pure V): LDS-transpose acc and write V^T [B,H][D][N].
__global__ __launch_bounds__(256, 3)
void gemm_qkv_k(const ushort* __restrict__ A, const ushort* __restrict__ Bt,
                ushort* __restrict__ qp, ushort* __restrict__ kp, ushort* __restrict__ vp) {
    __shared__ ushort smem[16384];   // As: [0,8192) Bs: [8192,16384); reused as T[128][128]
    int tid  = threadIdx.x;
    int wid  = tid >> 6, lane = tid & 63;
    int quad = lane >> 4, l16 = lane & 15;
    int wm = wid >> 1, wn = wid & 1;
    int rowbase = blockIdx.y * 128;
    int colbase = blockIdx.x * 128;

    f32x4 acc[4][4];
#pragma unroll
    for (int i = 0; i < 4; i++)
#pragma unroll
        for (int j = 0; j < 4; j++) acc[i][j] = (f32x4){0.f, 0.f, 0.f, 0.f};

    for (int k0 = 0; k0 < DIM; k0 += 64) {
#pragma unroll
        for (int p = 0; p < 2; p++) {
            int c = wid * 2 + p;
            int r = c * 16 + (lane >> 2);
            int ac = (lane & 3) * 8;
#pragma unroll
            for (int pnl = 0; pnl < 2; pnl++) {
                int cc = k0 + pnl * 32 + ac;
                gload_lds16(A  + (long)(rowbase + r) * DIM + cc,
                            &smem[pnl * 4096 + c * 16 * 32]);
                gload_lds16(Bt + (long)(colbase + r) * DIM + cc,
                            &smem[8192 + pnl * 4096 + c * 16 * 32]);
            }
        }
        __syncthreads();
#pragma unroll
        for (int pnl = 0; pnl < 2; pnl++) {
            bf16x8 fa[4], fb[4];
#pragma unroll
            for (int t = 0; t < 4; t++)
                fa[t] = *(const bf16x8*)(&smem[pnl * 4096 + (wm * 64 + t * 16 + l16) * 32 + quad * 8]);
#pragma unroll
            for (int t = 0; t < 4; t++)
                fb[t] = *(const bf16x8*)(&smem[8192 + pnl * 4096 + (wn * 64 + t * 16 + l16) * 32 + quad * 8]);
#pragma unroll
            for (int i = 0; i < 4; i++)
#pragma unroll
                for (int j = 0; j < 4; j++)
                    acc[i][j] = __builtin_amdgcn_mfma_f32_16x16x32_bf16(fa[i], fb[j], acc[i][j], 0, 0, 0);
        }
        __syncthreads();
    }

    if (colbase >= 2048) {
        // V block: acc -> T[col_local][row_local] -> coalesced V^T write
#pragma unroll
        for (int i = 0; i < 4; i++)
#pragma unroll
            for (int j = 0; j < 4; j++) {
                int cl = wn * 64 + j * 16 + l16;
                int rl = wm * 64 + i * 16 + quad * 4;
#pragma unroll
                for (int r = 0; r < 4; r++)
                    smem[cl * 128 + rl + r] = f2b(acc[i][j][r]);
            }
        __syncthreads();
        int b = rowbase >> 11, nnb = rowbase & 2047;
        int hbase = (colbase - 2048) >> 6;
#pragma unroll
        for (int i = 0; i < 8; i++) {
            int id = i * 256 + tid;           // 0..2047
            int cl = id >> 4;                 // local col 0..127
            int off = (id & 15) * 8;          // 0..120
            int hh = hbase + (cl >> 6), d = cl & 63;
            uint4 val = *(const uint4*)(&smem[cl * 128 + off]);
            *(uint4*)(vp + (((long)b * HEADS + hh) * HDIM + d) * SEQ + nnb + off) = val;
        }
    } else {
#pragma unroll
        for (int i = 0; i < 4; i++)
#pragma unroll
            for (int j = 0; j < 4; j++) {
                int m0  = rowbase + wm * 64 + i * 16 + quad * 4;
                int col = colbase + wn * 64 + j * 16 + l16;
                int part = col >> 10, rem = col & 1023;
                int head = rem >> 6, d = rem & 63;
                ushort* dst = (part == 0) ? qp : kp;
#pragma unroll
                for (int r = 0; r < 4; r++) {
                    float v = acc[i][j][r];
                    int mm = m0 + r;
                    int b = mm >> 11, nn = mm & 2047;
                    // q scale = 1/sqrt(64) * log2(e)  (softmax uses 2^x)
                    float sv = (part == 0) ? v * 0.18033688011f : v;
                    dst[((((long)b * HEADS + head) * SEQ + nn) << 6) + d] = f2b(sv);
                }
            }
    }
}

// ------- Proj GEMM: 128x64 tile, BK=64; grid 512 -----------------------------
__global__ __launch_bounds__(256, 3)
void gemm_proj_k(const ushort* __restrict__ A, const ushort* __restrict__ Bt,
                 const float* __restrict__ bias, const float* __restrict__ xres,
                 float* __restrict__ outp) {
    __shared__ ushort As[2][128][32];   // 16 KB
    __shared__ ushort Bs[2][64][32];    // 8 KB
    int tid  = threadIdx.x;
    int wid  = tid >> 6, lane = tid & 63;
    int quad = lane >> 4, l16 = lane & 15;
    int rowbase = blockIdx.y * 128;
    int colbase = blockIdx.x * 64;
    int arow = lane >> 2, acol = (lane & 3) * 8;

    f32x4 acc[2][4];
#pragma unroll
    for (int i = 0; i < 2; i++)
#pragma unroll
        for (int j = 0; j < 4; j++) acc[i][j] = (f32x4){0.f, 0.f, 0.f, 0.f};

    for (int k0 = 0; k0 < DIM; k0 += 64) {
#pragma unroll
        for (int p = 0; p < 2; p++) {
            int c = wid * 2 + p;
            int r = c * 16 + arow;
            int mm = rowbase + r;
            int bq = mm >> 11, nn = mm & 2047;
#pragma unroll
            for (int pnl = 0; pnl < 2; pnl++) {
                int cc = k0 + pnl * 32 + acol;
                int head = cc >> 6, d = cc & 63;
                gload_lds16(A + ((((long)bq * HEADS + head) * SEQ + nn) << 6) + d,
                            &As[pnl][c * 16][0]);
            }
        }
        {
            int r = wid * 16 + arow;
#pragma unroll
            for (int pnl = 0; pnl < 2; pnl++) {
                int cc = k0 + pnl * 32 + acol;
                gload_lds16(Bt + (long)(colbase + r) * DIM + cc, &Bs[pnl][wid * 16][0]);
            }
        }
        __syncthreads();
#pragma unroll
        for (int pnl = 0; pnl < 2; pnl++) {
            bf16x8 fa[2], fb[4];
#pragma unroll
            for (int t = 0; t < 2; t++)
                fa[t] = *(const bf16x8*)(&As[pnl][wid * 32 + t * 16 + l16][quad * 8]);
#pragma unroll
            for (int t = 0; t < 4; t++)
                fb[t] = *(const bf16x8*)(&Bs[pnl][t * 16 + l16][quad * 8]);
#pragma unroll
            for (int i = 0; i < 2; i++)
#pragma unroll
                for (int j = 0; j < 4; j++)
                    acc[i][j] = __builtin_amdgcn_mfma_f32_16x16x32_bf16(fa[i], fb[j], acc[i][j], 0, 0, 0);
        }
        __syncthreads();
    }

#pragma unroll
    for (int i = 0; i < 2; i++)
#pragma unroll
        for (int j = 0; j < 4; j++) {
            int m0  = rowbase + wid * 32 + i * 16 + quad * 4;
            int col = colbase + j * 16 + l16;
#pragma unroll
            for (int r = 0; r < 4; r++) {
                int mm = m0 + r;
                outp[(long)mm * DIM + col] = acc[i][j][r] + bias[col] + xres[(long)mm * DIM + col];
            }
        }
}

// ------- flash attention: KVBLK=64, 32x32 MFMA, in-register softmax ----------
// r2 structure (LDS-staged, swizzled, double-buffered) + T14 async-STAGE fix:
// the __syncthreads is ABOVE the prefetch-load issue, so the compiler's
// pre-barrier vmcnt(0) drain never exposes the prefetch latency -- the loads
// stay in flight under the whole MFMA+exp+pack body and are only waited on
// at the ds_write at the bottom (~2000 cy later).
// Both K and V LDS tiles are [64 rows][64 cols] (row stride = 128 B = full
// bank width), 16B-slot swizzle: physical_slot = logical_slot ^ (row & 7).
// Swapped QK^T: C[key][q], col=q=lane&31, row=key=(reg&3)+8*(reg>>2)+4*hi.
__global__ __launch_bounds__(256, 2)
void attn_k(ushort* qio, const ushort* __restrict__ kg,
            const ushort* __restrict__ vt) {
    __shared__ __align__(16) ushort Kp[2][4096];   // 16 KB: [buf] 64 key x 64 d
    __shared__ __align__(16) ushort Vs[2][4096];   // 16 KB: [buf] 64 d x 64 k
    int bh = blockIdx.y;
    int tid = threadIdx.x, wid = tid >> 6;
    int lane = tid & 63;
    int l31 = lane & 31, hi = lane >> 5;
    ushort* qh = qio + (long)bh * SEQ * HDIM;
    const ushort* kh = kg + (long)bh * SEQ * HDIM;
    const ushort* vh = vt + (long)bh * HDIM * SEQ;

    // staging: 256 threads x 2 shots x 16B for each of K and V.
    // shot s: row = (tid>>3)+32*s, chunk = tid&7  -> fully coalesced 128B rows.
    int srow = tid >> 3, schk = tid & 7;
    int sofs = srow * 64 + ((schk ^ (srow & 7)) * 8);   // shot1 ofs = sofs+2048
    const ushort* kbase = kh + (long)srow * HDIM + schk * 8;
    const ushort* vbase = vh + (long)srow * SEQ + schk * 8;

    int qrow0 = blockIdx.x * 128 + wid * 32;
    // Q B-frag: lane holds Q[q=l31][d = ks*16 + hi*8 + j]
    bf16x8 qf[4];
#pragma unroll
    for (int ks = 0; ks < 4; ks++)
        qf[ks] = *(const bf16x8*)(qh + (long)(qrow0 + l31) * HDIM + ks * 16 + hi * 8);

    f32x16 o0 = {}, o1 = {};                // PV acc: col=d=l31(+32)
    f32x4 lac = {0.f, 0.f, 0.f, 0.f};       // per-column (q) exp sums

    uint4 kr0 = *(const uint4*)(kbase);
    uint4 kr1 = *(const uint4*)(kbase + 32 * HDIM);
    uint4 vr0 = *(const uint4*)(vbase);
    uint4 vr1 = *(const uint4*)(vbase + 32 * SEQ);
    *(uint4*)(&Kp[0][sofs])        = kr0;
    *(uint4*)(&Kp[0][sofs + 2048]) = kr1;   // (srow+32)&7 == srow&7
    *(uint4*)(&Vs[0][sofs])        = vr0;
    *(uint4*)(&Vs[0][sofs + 2048]) = vr1;

    const int NIT = SEQ / 64;   // 32
    for (int it = 0; it < NIT; ++it) {
        int buf = it & 1;
        // barrier FIRST: separates prev iter's reads of buf^1 from this
        // iter's writes; vmcnt is already drained (prev loads consumed).
        __syncthreads();
        if (it + 1 < NIT) {
            int kt = (it + 1) * 64;
            kr0 = *(const uint4*)(kbase + (long)kt * HDIM);
            kr1 = *(const uint4*)(kbase + (long)(kt + 32) * HDIM);
            vr0 = *(const uint4*)(vbase + kt);
            vr1 = *(const uint4*)(vbase + 32 * SEQ + kt);
        }

        // QK^T: A = K[key][d], B = Q^T[d][q]; two independent 4-chains
        f32x16 sc0 = {}, sc1 = {};
        __builtin_amdgcn_s_setprio(1);
#pragma unroll
        for (int ks = 0; ks < 4; ks++) {
            int psl = ((2 * ks + hi) ^ (l31 & 7)) * 8;
            bf16x8 ka = *(const bf16x8*)(&Kp[buf][l31 * 64 + psl]);
            bf16x8 kb = *(const bf16x8*)(&Kp[buf][(32 + l31) * 64 + psl]);
            sc0 = __builtin_amdgcn_mfma_f32_32x32x16_bf16(ka, qf[ks], sc0, 0, 0, 0);
            sc1 = __builtin_amdgcn_mfma_f32_32x32x16_bf16(kb, qf[ks], sc1, 0, 0, 0);
        }
        __builtin_amdgcn_s_setprio(0);

        // softmax numerators: 2^(sc) (log2e folded into q scale)
        float e0[16], e1[16];
#pragma unroll
        for (int r = 0; r < 16; r++) { e0[r] = fexp2(sc0[r]); e1[r] = fexp2(sc1[r]); }
#pragma unroll
        for (int r = 0; r < 4; r++)
            lac += (f32x4){e0[4*r], e0[4*r+1], e0[4*r+2], e0[4*r+3]}
                 + (f32x4){e1[4*r], e1[4*r+1], e1[4*r+2], e1[4*r+3]};

        // P -> A-frags: 4 groups of 16 keys
        bf16x8 pa0 = pack8(e0[0], e0[1], e0[2],  e0[3],  e0[4],  e0[5],  e0[6],  e0[7]);
        bf16x8 pa1 = pack8(e0[8], e0[9], e0[10], e0[11], e0[12], e0[13], e0[14], e0[15]);
        bf16x8 pa2 = pack8(e1[0], e1[1], e1[2],  e1[3],  e1[4],  e1[5],  e1[6],  e1[7]);
        bf16x8 pa3 = pack8(e1[8], e1[9], e1[10], e1[11], e1[12], e1[13], e1[14], e1[15]);

        // PV: A = P[q][k], B = V[k][d] column slices; two independent 4-chains
        __builtin_amdgcn_s_setprio(1);
#pragma unroll
        for (int g = 0; g < 4; g++) {
            int psl = ((2 * g + hi) ^ (l31 & 7)) * 8;
            bf16x8 v0 = *(const bf16x8*)(&Vs[buf][l31 * 64 + psl]);
            bf16x8 v1 = *(const bf16x8*)(&Vs[buf][(32 + l31) * 64 + psl]);
            bf16x8 pg = (g == 0) ? pa0 : (g == 1) ? pa1 : (g == 2) ? pa2 : pa3;
            o0 = __builtin_amdgcn_mfma_f32_32x32x16_bf16(pg, v0, o0, 0, 0, 0);
            o1 = __builtin_amdgcn_mfma_f32_32x32x16_bf16(pg, v1, o1, 0, 0, 0);
        }
        __builtin_amdgcn_s_setprio(0);

        if (it + 1 < NIT) {
            // vmcnt wait lands here, ~2000 cy after issue -> fully hidden
            *(uint4*)(&Kp[buf ^ 1][sofs])        = kr0;
            *(uint4*)(&Kp[buf ^ 1][sofs + 2048]) = kr1;
            *(uint4*)(&Vs[buf ^ 1][sofs])        = vr0;
            *(uint4*)(&Vs[buf ^ 1][sofs + 2048]) = vr1;
        }
    }

    // denominators: column q sums split across lane pair (q, q+32)
    float t = lac[0] + lac[1] + lac[2] + lac[3];
    t += __shfl_xor(t, 32);
    float linv = 1.0f / t;          // valid in lanes q and q+32 for column q=l31
#pragma unroll
    for (int r = 0; r < 16; r++) {
        int qrow = (r & 3) + 8 * (r >> 2) + 4 * hi;
        float lr = __shfl(linv, qrow);        // lane qrow holds 1/sum for q=qrow
        long ro = (long)(qrow0 + qrow) * HDIM;
        qh[ro + l31]      = f2b(o0[r] * lr);
        qh[ro + 32 + l31] = f2b(o1[r] * lr);
    }
}

// ------- launch --------------------------------------------------------------
extern "C" void kernel_launch(void* const* d_in, const int* in_sizes, int n_in,
                              void* d_out, int out_size, void* d_ws, size_t ws_size,
                              hipStream_t stream) {
    const float* x      = (const float*)d_in[0];
    const float* w_qkv  = (const float*)d_in[1];
    const float* w_proj = (const float*)d_in[2];
    const float* b_proj = (const float*)d_in[3];
    const float* gamma  = (const float*)d_in[4];
    const float* beta   = (const float*)d_in[5];
    float* out = (float*)d_out;

    // workspace: 19M bf16 elements = 38 MB
    ushort* ws   = (ushort*)d_ws;
    ushort* h    = ws;                      // 4M: LN output
    ushort* wqt  = ws + (size_t)4 * MEG;    // 3M: w_qkv^T (bf16)
    ushort* qb   = ws + (size_t)7 * MEG;    // 4M: q (pre-scaled), then attn out (q-layout)
    ushort* kb   = ws + (size_t)11 * MEG;   // 4M: k, then w_proj^T
    ushort* vtb  = ws + (size_t)15 * MEG;   // 4M: V^T [B,H][D][N] (written by QKV epilogue)

    // 1) transpose+cast w_qkv f32[K][3N] -> bf16 [3N][K]
    transpose_f2b_k<<<dim3(3 * DIM / 32, DIM / 32), dim3(32, 8), 0, stream>>>(
        w_qkv, wqt, DIM, 3 * DIM);
    // 2) layernorm f32 -> bf16 h
    ln_k<<<dim3(TOK), dim3(256), 0, stream>>>(x, gamma, beta, h);
    // 3) qkv gemm: scatter q/k, V^T written directly (fused transpose)
    gemm_qkv_k<<<dim3(3 * DIM / 128, TOK / 128), dim3(256), 0, stream>>>(
        h, wqt, qb, kb, vtb);
    // 4) flash attention; output overwrites q buffer in q-layout
    attn_k<<<dim3(SEQ / 128, BATCH * HEADS), dim3(256), 0, stream>>>(qb, kb, vtb);
    // 5) transpose+cast w_proj into dead k slot
    transpose_f2b_k<<<dim3(DIM / 32, DIM / 32), dim3(32, 8), 0, stream>>>(
        w_proj, kb, DIM, DIM);
    // 6) proj gemm (+fp32 bias +fp32 residual) -> fp32 out, 128x64 tiles
    gemm_proj_k<<<dim3(DIM / 64, TOK / 128), dim3(256), 0, stream>>>(
        qb, kb, b_proj, x, out);
}

// Round 5
// 188.531 us; speedup vs baseline: 1.3642x; 1.0096x over previous
//
#include <hip/hip_runtime.h>

#define DIM   1024
#define HEADS 16
#define HDIM  64
#define BATCH 2
#define SEQ   2048
#define TOK   (BATCH*SEQ)   // 4096
#define MEG   1048576

typedef __bf16 bf16x8 __attribute__((ext_vector_type(8)));
typedef float  f32x4  __attribute__((ext_vector_type(4)));
typedef float  f32x16 __attribute__((ext_vector_type(16)));

__device__ __forceinline__ float b2f(ushort u) {
    union { unsigned int u32; float f; } x; x.u32 = ((unsigned int)u) << 16; return x.f;
}
__device__ __forceinline__ ushort f2b(float f) {
    union { float f; unsigned int u32; } x; x.f = f;
    unsigned int r = x.u32 + 0x7FFFu + ((x.u32 >> 16) & 1u);
    return (ushort)(r >> 16);
}
// async global->LDS, 16B per lane; lds dest = wave-uniform base + lane*16
__device__ __forceinline__ void gload_lds16(const ushort* g, void* l) {
    __builtin_amdgcn_global_load_lds((const __attribute__((address_space(1))) void*)g,
                                     (__attribute__((address_space(3))) void*)l, 16, 0, 0);
}
__device__ __forceinline__ float fexp2(float x) {   // 2^x, single v_exp_f32
    float r; asm("v_exp_f32 %0, %1" : "=v"(r) : "v"(x)); return r;
}
__device__ __forceinline__ unsigned int cvtpk_bf16(float lo, float hi) {
    unsigned int r; asm("v_cvt_pk_bf16_f32 %0, %1, %2" : "=v"(r) : "v"(lo), "v"(hi)); return r;
}
// swap a's upper 32 lanes with b's lower 32 lanes
__device__ __forceinline__ void plane32swap(unsigned int &a, unsigned int &b) {
    asm("v_permlane32_swap_b32 %0, %1" : "+v"(a), "+v"(b));
}
// pack 8 consecutive-key exp values (MFMA C-layout regs) into one A-frag
__device__ __forceinline__ bf16x8 pack8(float e0, float e1, float e2, float e3,
                                        float e4, float e5, float e6, float e7) {
    unsigned int a = cvtpk_bf16(e0, e1), b = cvtpk_bf16(e2, e3);
    unsigned int c = cvtpk_bf16(e4, e5), d = cvtpk_bf16(e6, e7);
    plane32swap(a, c); plane32swap(b, d);
    union { unsigned int u[4]; bf16x8 v; } r;
    r.u[0] = a; r.u[1] = b; r.u[2] = c; r.u[3] = d;
    return r.v;
}
// exp 8 score regs (one 16-key half-group), accumulate denominators, pack
__device__ __forceinline__ bf16x8 exp_pack8(const f32x16 &sc, int base, f32x4 &lac) {
    float e0 = fexp2(sc[base + 0]), e1 = fexp2(sc[base + 1]);
    float e2 = fexp2(sc[base + 2]), e3 = fexp2(sc[base + 3]);
    float e4 = fexp2(sc[base + 4]), e5 = fexp2(sc[base + 5]);
    float e6 = fexp2(sc[base + 6]), e7 = fexp2(sc[base + 7]);
    lac += (f32x4){e0, e1, e2, e3};
    lac += (f32x4){e4, e5, e6, e7};
    return pack8(e0, e1, e2, e3, e4, e5, e6, e7);
}

// ------- tiled transpose + fp32->bf16 cast: src f32[R][Cc] -> dst bf16[Cc][R]
__global__ void transpose_f2b_k(const float* __restrict__ src, ushort* __restrict__ dst,
                                int R, int Cc) {
    __shared__ ushort tile[32][33];
    int c0 = blockIdx.x * 32, r0 = blockIdx.y * 32;
    int tx = threadIdx.x, ty = threadIdx.y;   // 32 x 8
#pragma unroll
    for (int i = 0; i < 4; i++)
        tile[ty + 8 * i][tx] = f2b(src[(long)(r0 + ty + 8 * i) * Cc + c0 + tx]);
    __syncthreads();
#pragma unroll
    for (int i = 0; i < 4; i++)
        dst[(long)(c0 + ty + 8 * i) * R + r0 + tx] = tile[tx][ty + 8 * i];
}

// ------- LayerNorm: one block per token, fp32 in -> bf16 out -----------------
__global__ __launch_bounds__(256)
void ln_k(const float* __restrict__ x, const float* __restrict__ gamma,
          const float* __restrict__ beta, ushort* __restrict__ h) {
    __shared__ float red[8];
    int row = blockIdx.x, tid = threadIdx.x;
    const float* xr = x + (long)row * DIM;
    float4 xv = *(const float4*)(xr + tid * 4);
    float s1 = xv.x + xv.y + xv.z + xv.w;
    float s2 = xv.x * xv.x + xv.y * xv.y + xv.z * xv.z + xv.w * xv.w;
#pragma unroll
    for (int off = 32; off; off >>= 1) {
        s1 += __shfl_down(s1, off);
        s2 += __shfl_down(s2, off);
    }
    int wid = tid >> 6, lane = tid & 63;
    if (lane == 0) { red[wid * 2] = s1; red[wid * 2 + 1] = s2; }
    __syncthreads();
    s1 = red[0] + red[2] + red[4] + red[6];
    s2 = red[1] + red[3] + red[5] + red[7];
    float mu  = s1 * (1.0f / DIM);
    float var = s2 * (1.0f / DIM) - mu * mu;
    float rs  = rsqrtf(var + 1e-5f);
    float4 gv = *(const float4*)(gamma + tid * 4);
    float4 bv = *(const float4*)(beta + tid * 4);
    ushort4 ov;
    ov.x = f2b((xv.x - mu) * rs * gv.x + bv.x);
    ov.y = f2b((xv.y - mu) * rs * gv.y + bv.y);
    ov.z = f2b((xv.z - mu) * rs * gv.z + bv.z);
    ov.w = f2b((xv.w - mu) * rs * gv.w + bv.w);
    *(ushort4*)(h + (long)row * DIM + tid * 4) = ov;
}

// ------- QKV GEMM: 128x128 tile, BK=64, global_load_lds staging --------------
// Col-tiles < 2048: scatter q/k to [B,H,N,D] (q pre-scaled 1/8 * log2e so the
// attention softmax can use bare v_exp_f32 = 2^x).
// Col-tiles >= 2048 (pure V): LDS-transpose acc and write V^T [B,H][D][N].
__global__ __launch_bounds__(256, 3)
void gemm_qkv_k(const ushort* __restrict__ A, const ushort* __restrict__ Bt,
                ushort* __restrict__ qp, ushort* __restrict__ kp, ushort* __restrict__ vp) {
    __shared__ ushort smem[16384];   // As: [0,8192) Bs: [8192,16384); reused as T[128][128]
    int tid  = threadIdx.x;
    int wid  = tid >> 6, lane = tid & 63;
    int quad = lane >> 4, l16 = lane & 15;
    int wm = wid >> 1, wn = wid & 1;
    int rowbase = blockIdx.y * 128;
    int colbase = blockIdx.x * 128;

    f32x4 acc[4][4];
#pragma unroll
    for (int i = 0; i < 4; i++)
#pragma unroll
        for (int j = 0; j < 4; j++) acc[i][j] = (f32x4){0.f, 0.f, 0.f, 0.f};

    for (int k0 = 0; k0 < DIM; k0 += 64) {
#pragma unroll
        for (int p = 0; p < 2; p++) {
            int c = wid * 2 + p;
            int r = c * 16 + (lane >> 2);
            int ac = (lane & 3) * 8;
#pragma unroll
            for (int pnl = 0; pnl < 2; pnl++) {
                int cc = k0 + pnl * 32 + ac;
                gload_lds16(A  + (long)(rowbase + r) * DIM + cc,
                            &smem[pnl * 4096 + c * 16 * 32]);
                gload_lds16(Bt + (long)(colbase + r) * DIM + cc,
                            &smem[8192 + pnl * 4096 + c * 16 * 32]);
            }
        }
        __syncthreads();
#pragma unroll
        for (int pnl = 0; pnl < 2; pnl++) {
            bf16x8 fa[4], fb[4];
#pragma unroll
            for (int t = 0; t < 4; t++)
                fa[t] = *(const bf16x8*)(&smem[pnl * 4096 + (wm * 64 + t * 16 + l16) * 32 + quad * 8]);
#pragma unroll
            for (int t = 0; t < 4; t++)
                fb[t] = *(const bf16x8*)(&smem[8192 + pnl * 4096 + (wn * 64 + t * 16 + l16) * 32 + quad * 8]);
#pragma unroll
            for (int i = 0; i < 4; i++)
#pragma unroll
                for (int j = 0; j < 4; j++)
                    acc[i][j] = __builtin_amdgcn_mfma_f32_16x16x32_bf16(fa[i], fb[j], acc[i][j], 0, 0, 0);
        }
        __syncthreads();
    }

    if (colbase >= 2048) {
        // V block: acc -> T[col_local][row_local] -> coalesced V^T write
#pragma unroll
        for (int i = 0; i < 4; i++)
#pragma unroll
            for (int j = 0; j < 4; j++) {
                int cl = wn * 64 + j * 16 + l16;
                int rl = wm * 64 + i * 16 + quad * 4;
#pragma unroll
                for (int r = 0; r < 4; r++)
                    smem[cl * 128 + rl + r] = f2b(acc[i][j][r]);
            }
        __syncthreads();
        int b = rowbase >> 11, nnb = rowbase & 2047;
        int hbase = (colbase - 2048) >> 6;
#pragma unroll
        for (int i = 0; i < 8; i++) {
            int id = i * 256 + tid;           // 0..2047
            int cl = id >> 4;                 // local col 0..127
            int off = (id & 15) * 8;          // 0..120
            int hh = hbase + (cl >> 6), d = cl & 63;
            uint4 val = *(const uint4*)(&smem[cl * 128 + off]);
            *(uint4*)(vp + (((long)b * HEADS + hh) * HDIM + d) * SEQ + nnb + off) = val;
        }
    } else {
#pragma unroll
        for (int i = 0; i < 4; i++)
#pragma unroll
            for (int j = 0; j < 4; j++) {
                int m0  = rowbase + wm * 64 + i * 16 + quad * 4;
                int col = colbase + wn * 64 + j * 16 + l16;
                int part = col >> 10, rem = col & 1023;
                int head = rem >> 6, d = rem & 63;
                ushort* dst = (part == 0) ? qp : kp;
#pragma unroll
                for (int r = 0; r < 4; r++) {
                    float v = acc[i][j][r];
                    int mm = m0 + r;
                    int b = mm >> 11, nn = mm & 2047;
                    // q scale = 1/sqrt(64) * log2(e)  (softmax uses 2^x)
                    float sv = (part == 0) ? v * 0.18033688011f : v;
                    dst[((((long)b * HEADS + head) * SEQ + nn) << 6) + d] = f2b(sv);
                }
            }
    }
}

// ------- Proj GEMM: 128x64 tile, BK=64; grid 512 -----------------------------
__global__ __launch_bounds__(256, 3)
void gemm_proj_k(const ushort* __restrict__ A, const ushort* __restrict__ Bt,
                 const float* __restrict__ bias, const float* __restrict__ xres,
                 float* __restrict__ outp) {
    __shared__ ushort As[2][128][32];   // 16 KB
    __shared__ ushort Bs[2][64][32];    // 8 KB
    int tid  = threadIdx.x;
    int wid  = tid >> 6, lane = tid & 63;
    int quad = lane >> 4, l16 = lane & 15;
    int rowbase = blockIdx.y * 128;
    int colbase = blockIdx.x * 64;
    int arow = lane >> 2, acol = (lane & 3) * 8;

    f32x4 acc[2][4];
#pragma unroll
    for (int i = 0; i < 2; i++)
#pragma unroll
        for (int j = 0; j < 4; j++) acc[i][j] = (f32x4){0.f, 0.f, 0.f, 0.f};

    for (int k0 = 0; k0 < DIM; k0 += 64) {
#pragma unroll
        for (int p = 0; p < 2; p++) {
            int c = wid * 2 + p;
            int r = c * 16 + arow;
            int mm = rowbase + r;
            int bq = mm >> 11, nn = mm & 2047;
#pragma unroll
            for (int pnl = 0; pnl < 2; pnl++) {
                int cc = k0 + pnl * 32 + acol;
                int head = cc >> 6, d = cc & 63;
                gload_lds16(A + ((((long)bq * HEADS + head) * SEQ + nn) << 6) + d,
                            &As[pnl][c * 16][0]);
            }
        }
        {
            int r = wid * 16 + arow;
#pragma unroll
            for (int pnl = 0; pnl < 2; pnl++) {
                int cc = k0 + pnl * 32 + acol;
                gload_lds16(Bt + (long)(colbase + r) * DIM + cc, &Bs[pnl][wid * 16][0]);
            }
        }
        __syncthreads();
#pragma unroll
        for (int pnl = 0; pnl < 2; pnl++) {
            bf16x8 fa[2], fb[4];
#pragma unroll
            for (int t = 0; t < 2; t++)
                fa[t] = *(const bf16x8*)(&As[pnl][wid * 32 + t * 16 + l16][quad * 8]);
#pragma unroll
            for (int t = 0; t < 4; t++)
                fb[t] = *(const bf16x8*)(&Bs[pnl][t * 16 + l16][quad * 8]);
#pragma unroll
            for (int i = 0; i < 2; i++)
#pragma unroll
                for (int j = 0; j < 4; j++)
                    acc[i][j] = __builtin_amdgcn_mfma_f32_16x16x32_bf16(fa[i], fb[j], acc[i][j], 0, 0, 0);
        }
        __syncthreads();
    }

#pragma unroll
    for (int i = 0; i < 2; i++)
#pragma unroll
        for (int j = 0; j < 4; j++) {
            int m0  = rowbase + wid * 32 + i * 16 + quad * 4;
            int col = colbase + j * 16 + l16;
#pragma unroll
            for (int r = 0; r < 4; r++) {
                int mm = m0 + r;
                outp[(long)mm * DIM + col] = acc[i][j][r] + bias[col] + xres[(long)mm * DIM + col];
            }
        }
}

// ------- flash attention: software-pipelined (QK(t+1) || softmax(t) || PV(t))
// Iteration-level pipeline (T15): score regs sc(t) are computed one iteration
// AHEAD (QK^T(t+1) issues in iter t while exp/pack(t) runs on the VALU) --
// removes QK from the per-iter critical chain and gives the scheduler
// independent MFMA + VALU streams inside one wave.
// 3-slot LDS ring (48 KB): iter t reads K from slot[(t+1)%3], V from
// slot[t%3], stages tile t+2 into slot[(t+2)%3]. One barrier per iter
// (bottom): writes to slot s are separated from their previous reader
// (tile t-1, same physical slot) by that barrier.
// Tiles are [64 rows][64 cols] (row stride 128 B = full bank width),
// 16B-slot swizzle: physical_slot = logical_slot ^ (row & 7).
// Swapped QK^T: C[key][q], col=q=lane&31, row=key=(reg&3)+8*(reg>>2)+4*hi.
__global__ __launch_bounds__(256, 2)
void attn_k(ushort* qio, const ushort* __restrict__ kg,
            const ushort* __restrict__ vt) {
    __shared__ __align__(16) ushort lds[3 * 8192];   // slot: K[0,4096) V[4096,8192)
    int bh = blockIdx.y;
    int tid = threadIdx.x, wid = tid >> 6;
    int lane = tid & 63;
    int l31 = lane & 31, hi = lane >> 5;
    ushort* qh = qio + (long)bh * SEQ * HDIM;
    const ushort* kh = kg + (long)bh * SEQ * HDIM;
    const ushort* vh = vt + (long)bh * HDIM * SEQ;

    // staging: 256 threads x 2 shots x 16B for each of K and V.
    // shot s: row = (tid>>3)+32*s, chunk = tid&7  -> fully coalesced 128B rows.
    int srow = tid >> 3, schk = tid & 7;
    int sofs = srow * 64 + ((schk ^ (srow & 7)) * 8);   // shot1 ofs = sofs+2048
    const ushort* kbase = kh + (long)srow * HDIM + schk * 8;
    const ushort* vbase = vh + (long)srow * SEQ + schk * 8;

    int qrow0 = blockIdx.x * 128 + wid * 32;
    // Q B-frag: lane holds Q[q=l31][d = ks*16 + hi*8 + j]
    bf16x8 qf[4];
#pragma unroll
    for (int ks = 0; ks < 4; ks++)
        qf[ks] = *(const bf16x8*)(qh + (long)(qrow0 + l31) * HDIM + ks * 16 + hi * 8);

    f32x16 o0 = {}, o1 = {};                // PV acc: col=d=l31(+32)
    f32x4 lac = {0.f, 0.f, 0.f, 0.f};       // per-column (q) exp sums

    // prologue: stage tiles 0 and 1 into slots 0 and 1
    {
        uint4 a0 = *(const uint4*)(kbase);
        uint4 a1 = *(const uint4*)(kbase + 32 * HDIM);
        uint4 b0 = *(const uint4*)(vbase);
        uint4 b1 = *(const uint4*)(vbase + 32 * SEQ);
        uint4 c0 = *(const uint4*)(kbase + 64 * HDIM);
        uint4 c1 = *(const uint4*)(kbase + 96 * HDIM);
        uint4 d0 = *(const uint4*)(vbase + 64);
        uint4 d1 = *(const uint4*)(vbase + 32 * SEQ + 64);
        *(uint4*)(&lds[sofs])               = a0;
        *(uint4*)(&lds[sofs + 2048])        = a1;   // (srow+32)&7 == srow&7
        *(uint4*)(&lds[4096 + sofs])        = b0;
        *(uint4*)(&lds[4096 + sofs + 2048]) = b1;
        *(uint4*)(&lds[8192 + sofs])               = c0;
        *(uint4*)(&lds[8192 + sofs + 2048])        = c1;
        *(uint4*)(&lds[8192 + 4096 + sofs])        = d0;
        *(uint4*)(&lds[8192 + 4096 + sofs + 2048]) = d1;
    }
    __syncthreads();

    // initial QK^T(0) from slot 0
    f32x16 sc0 = {}, sc1 = {};
    __builtin_amdgcn_s_setprio(1);
#pragma unroll
    for (int ks = 0; ks < 4; ks++) {
        int psl = ((2 * ks + hi) ^ (l31 & 7)) * 8;
        bf16x8 ka = *(const bf16x8*)(&lds[l31 * 64 + psl]);
        bf16x8 kb = *(const bf16x8*)(&lds[(32 + l31) * 64 + psl]);
        sc0 = __builtin_amdgcn_mfma_f32_32x32x16_bf16(ka, qf[ks], sc0, 0, 0, 0);
        sc1 = __builtin_amdgcn_mfma_f32_32x32x16_bf16(kb, qf[ks], sc1, 0, 0, 0);
    }
    __builtin_amdgcn_s_setprio(0);

    const int NIT = SEQ / 64;   // 32
    int s0 = 0, s1 = 1, s2 = 2;
    for (int t = 0; t < NIT; ++t) {
        uint4 kr0, kr1, vr0, vr1;
        bool stage = (t + 2 < NIT);
        if (stage) {
            int kt = (t + 2) * 64;
            kr0 = *(const uint4*)(kbase + (long)kt * HDIM);
            kr1 = *(const uint4*)(kbase + (long)(kt + 32) * HDIM);
            vr0 = *(const uint4*)(vbase + kt);
            vr1 = *(const uint4*)(vbase + 32 * SEQ + kt);
        }

        // QK^T(t+1) from K slot s1 -- independent of this iter's softmax/PV
        f32x16 n0 = {}, n1 = {};
        if (t + 1 < NIT) {
            const ushort* Kb = &lds[s1 * 8192];
            __builtin_amdgcn_s_setprio(1);
#pragma unroll
            for (int ks = 0; ks < 4; ks++) {
                int psl = ((2 * ks + hi) ^ (l31 & 7)) * 8;
                bf16x8 ka = *(const bf16x8*)(&Kb[l31 * 64 + psl]);
                bf16x8 kb = *(const bf16x8*)(&Kb[(32 + l31) * 64 + psl]);
                n0 = __builtin_amdgcn_mfma_f32_32x32x16_bf16(ka, qf[ks], n0, 0, 0, 0);
                n1 = __builtin_amdgcn_mfma_f32_32x32x16_bf16(kb, qf[ks], n1, 0, 0, 0);
            }
            __builtin_amdgcn_s_setprio(0);
        }

        // softmax(t): exp + denom + pack (VALU/trans -- overlaps QK MFMAs)
        bf16x8 pa0 = exp_pack8(sc0, 0, lac);
        bf16x8 pa1 = exp_pack8(sc0, 8, lac);
        bf16x8 pa2 = exp_pack8(sc1, 0, lac);
        bf16x8 pa3 = exp_pack8(sc1, 8, lac);

        // PV(t): A = P[q][k], B = V[k][d] column slices from V slot s0
        {
            const ushort* Vb = &lds[s0 * 8192 + 4096];
            __builtin_amdgcn_s_setprio(1);
#pragma unroll
            for (int g = 0; g < 4; g++) {
                int psl = ((2 * g + hi) ^ (l31 & 7)) * 8;
                bf16x8 v0 = *(const bf16x8*)(&Vb[l31 * 64 + psl]);
                bf16x8 v1 = *(const bf16x8*)(&Vb[(32 + l31) * 64 + psl]);
                bf16x8 pg = (g == 0) ? pa0 : (g == 1) ? pa1 : (g == 2) ? pa2 : pa3;
                o0 = __builtin_amdgcn_mfma_f32_32x32x16_bf16(pg, v0, o0, 0, 0, 0);
                o1 = __builtin_amdgcn_mfma_f32_32x32x16_bf16(pg, v1, o1, 0, 0, 0);
            }
            __builtin_amdgcn_s_setprio(0);
        }

        if (stage) {
            ushort* Sb = &lds[s2 * 8192];
            *(uint4*)(&Sb[sofs])               = kr0;
            *(uint4*)(&Sb[sofs + 2048])        = kr1;
            *(uint4*)(&Sb[4096 + sofs])        = vr0;
            *(uint4*)(&Sb[4096 + sofs + 2048]) = vr1;
        }

        sc0 = n0; sc1 = n1;
        int tmp = s0; s0 = s1; s1 = s2; s2 = tmp;
        __syncthreads();
    }

    // denominators: column q sums split across lane pair (q, q+32)
    float t = lac[0] + lac[1] + lac[2] + lac[3];
    t += __shfl_xor(t, 32);
    float linv = 1.0f / t;          // valid in lanes q and q+32 for column q=l31
#pragma unroll
    for (int r = 0; r < 16; r++) {
        int qrow = (r & 3) + 8 * (r >> 2) + 4 * hi;
        float lr = __shfl(linv, qrow);        // lane qrow holds 1/sum for q=qrow
        long ro = (long)(qrow0 + qrow) * HDIM;
        qh[ro + l31]      = f2b(o0[r] * lr);
        qh[ro + 32 + l31] = f2b(o1[r] * lr);
    }
}

// ------- launch --------------------------------------------------------------
extern "C" void kernel_launch(void* const* d_in, const int* in_sizes, int n_in,
                              void* d_out, int out_size, void* d_ws, size_t ws_size,
                              hipStream_t stream) {
    const float* x      = (const float*)d_in[0];
    const float* w_qkv  = (const float*)d_in[1];
    const float* w_proj = (const float*)d_in[2];
    const float* b_proj = (const float*)d_in[3];
    const float* gamma  = (const float*)d_in[4];
    const float* beta   = (const float*)d_in[5];
    float* out = (float*)d_out;

    // workspace: 19M bf16 elements = 38 MB
    ushort* ws   = (ushort*)d_ws;
    ushort* h    = ws;                      // 4M: LN output
    ushort* wqt  = ws + (size_t)4 * MEG;    // 3M: w_qkv^T (bf16)
    ushort* qb   = ws + (size_t)7 * MEG;    // 4M: q (pre-scaled), then attn out (q-layout)
    ushort* kb   = ws + (size_t)11 * MEG;   // 4M: k, then w_proj^T
    ushort* vtb  = ws + (size_t)15 * MEG;   // 4M: V^T [B,H][D][N] (written by QKV epilogue)

    // 1) transpose+cast w_qkv f32[K][3N] -> bf16 [3N][K]
    transpose_f2b_k<<<dim3(3 * DIM / 32, DIM / 32), dim3(32, 8), 0, stream>>>(
        w_qkv, wqt, DIM, 3 * DIM);
    // 2) layernorm f32 -> bf16 h
    ln_k<<<dim3(TOK), dim3(256), 0, stream>>>(x, gamma, beta, h);
    // 3) qkv gemm: scatter q/k, V^T written directly (fused transpose)
    gemm_qkv_k<<<dim3(3 * DIM / 128, TOK / 128), dim3(256), 0, stream>>>(
        h, wqt, qb, kb, vtb);
    // 4) flash attention; output overwrites q buffer in q-layout
    attn_k<<<dim3(SEQ / 128, BATCH * HEADS), dim3(256), 0, stream>>>(qb, kb, vtb);
    // 5) transpose+cast w_proj into dead k slot
    transpose_f2b_k<<<dim3(DIM / 32, DIM / 32), dim3(32, 8), 0, stream>>>(
        w_proj, kb, DIM, DIM);
    // 6) proj gemm (+fp32 bias +fp32 residual) -> fp32 out, 128x64 tiles
    gemm_proj_k<<<dim3(DIM / 64, TOK / 128), dim3(256), 0, stream>>>(
        qb, kb, b_proj, x, out);
}

// Round 6
// 183.503 us; speedup vs baseline: 1.4016x; 1.0274x over previous
//
#include <hip/hip_runtime.h>

#define DIM   1024
#define HEADS 16
#define HDIM  64
#define BATCH 2
#define SEQ   2048
#define TOK   (BATCH*SEQ)   // 4096
#define MEG   1048576

typedef __bf16 bf16x8 __attribute__((ext_vector_type(8)));
typedef float  f32x4  __attribute__((ext_vector_type(4)));
typedef float  f32x16 __attribute__((ext_vector_type(16)));

__device__ __forceinline__ float b2f(ushort u) {
    union { unsigned int u32; float f; } x; x.u32 = ((unsigned int)u) << 16; return x.f;
}
__device__ __forceinline__ ushort f2b(float f) {
    union { float f; unsigned int u32; } x; x.f = f;
    unsigned int r = x.u32 + 0x7FFFu + ((x.u32 >> 16) & 1u);
    return (ushort)(r >> 16);
}
// async global->LDS, 16B per lane; lds dest = wave-uniform base + lane*16
__device__ __forceinline__ void gload_lds16(const ushort* g, void* l) {
    __builtin_amdgcn_global_load_lds((const __attribute__((address_space(1))) void*)g,
                                     (__attribute__((address_space(3))) void*)l, 16, 0, 0);
}
__device__ __forceinline__ float fexp2(float x) {   // 2^x, single v_exp_f32
    float r; asm("v_exp_f32 %0, %1" : "=v"(r) : "v"(x)); return r;
}
__device__ __forceinline__ unsigned int cvtpk_bf16(float lo, float hi) {
    unsigned int r; asm("v_cvt_pk_bf16_f32 %0, %1, %2" : "=v"(r) : "v"(lo), "v"(hi)); return r;
}
// swap a's upper 32 lanes with b's lower 32 lanes
__device__ __forceinline__ void plane32swap(unsigned int &a, unsigned int &b) {
    asm("v_permlane32_swap_b32 %0, %1" : "+v"(a), "+v"(b));
}
// pack 8 consecutive-key exp values (MFMA C-layout regs) into one A-frag
__device__ __forceinline__ bf16x8 pack8(float e0, float e1, float e2, float e3,
                                        float e4, float e5, float e6, float e7) {
    unsigned int a = cvtpk_bf16(e0, e1), b = cvtpk_bf16(e2, e3);
    unsigned int c = cvtpk_bf16(e4, e5), d = cvtpk_bf16(e6, e7);
    plane32swap(a, c); plane32swap(b, d);
    union { unsigned int u[4]; bf16x8 v; } r;
    r.u[0] = a; r.u[1] = b; r.u[2] = c; r.u[3] = d;
    return r.v;
}

// ------- tiled transpose + fp32->bf16 cast: src f32[R][Cc] -> dst bf16[Cc][R]
__global__ void transpose_f2b_k(const float* __restrict__ src, ushort* __restrict__ dst,
                                int R, int Cc) {
    __shared__ ushort tile[32][33];
    int c0 = blockIdx.x * 32, r0 = blockIdx.y * 32;
    int tx = threadIdx.x, ty = threadIdx.y;   // 32 x 8
#pragma unroll
    for (int i = 0; i < 4; i++)
        tile[ty + 8 * i][tx] = f2b(src[(long)(r0 + ty + 8 * i) * Cc + c0 + tx]);
    __syncthreads();
#pragma unroll
    for (int i = 0; i < 4; i++)
        dst[(long)(c0 + ty + 8 * i) * R + r0 + tx] = tile[tx][ty + 8 * i];
}

// ------- LayerNorm: one block per token, fp32 in -> bf16 out -----------------
__global__ __launch_bounds__(256)
void ln_k(const float* __restrict__ x, const float* __restrict__ gamma,
          const float* __restrict__ beta, ushort* __restrict__ h) {
    __shared__ float red[8];
    int row = blockIdx.x, tid = threadIdx.x;
    const float* xr = x + (long)row * DIM;
    float4 xv = *(const float4*)(xr + tid * 4);
    float s1 = xv.x + xv.y + xv.z + xv.w;
    float s2 = xv.x * xv.x + xv.y * xv.y + xv.z * xv.z + xv.w * xv.w;
#pragma unroll
    for (int off = 32; off; off >>= 1) {
        s1 += __shfl_down(s1, off);
        s2 += __shfl_down(s2, off);
    }
    int wid = tid >> 6, lane = tid & 63;
    if (lane == 0) { red[wid * 2] = s1; red[wid * 2 + 1] = s2; }
    __syncthreads();
    s1 = red[0] + red[2] + red[4] + red[6];
    s2 = red[1] + red[3] + red[5] + red[7];
    float mu  = s1 * (1.0f / DIM);
    float var = s2 * (1.0f / DIM) - mu * mu;
    float rs  = rsqrtf(var + 1e-5f);
    float4 gv = *(const float4*)(gamma + tid * 4);
    float4 bv = *(const float4*)(beta + tid * 4);
    ushort4 ov;
    ov.x = f2b((xv.x - mu) * rs * gv.x + bv.x);
    ov.y = f2b((xv.y - mu) * rs * gv.y + bv.y);
    ov.z = f2b((xv.z - mu) * rs * gv.z + bv.z);
    ov.w = f2b((xv.w - mu) * rs * gv.w + bv.w);
    *(ushort4*)(h + (long)row * DIM + tid * 4) = ov;
}

// ------- QKV GEMM: 128x128 tile, BK=64, global_load_lds staging --------------
// Epilogues stage through padded T[128][136] (stride 272 B: 16B-aligned,
// breaks the 256B bank period -> no 16-way conflicts) and write coalesced
// uint4 (128B per head-segment) instead of scattered 2B stores.
// Col-tiles < 2048: q/k to [B,H,N,D] (q pre-scaled 1/8 * log2e).
// Col-tiles >= 2048 (pure V): transposed -> V^T [B,H][D][N].
__global__ __launch_bounds__(256, 3)
void gemm_qkv_k(const ushort* __restrict__ A, const ushort* __restrict__ Bt,
                ushort* __restrict__ qp, ushort* __restrict__ kp, ushort* __restrict__ vp) {
    __shared__ __align__(16) ushort smem[17408];  // loop: [0,16384); epi: T[128][136]
    int tid  = threadIdx.x;
    int wid  = tid >> 6, lane = tid & 63;
    int quad = lane >> 4, l16 = lane & 15;
    int wm = wid >> 1, wn = wid & 1;
    int rowbase = blockIdx.y * 128;
    int colbase = blockIdx.x * 128;

    f32x4 acc[4][4];
#pragma unroll
    for (int i = 0; i < 4; i++)
#pragma unroll
        for (int j = 0; j < 4; j++) acc[i][j] = (f32x4){0.f, 0.f, 0.f, 0.f};

    for (int k0 = 0; k0 < DIM; k0 += 64) {
#pragma unroll
        for (int p = 0; p < 2; p++) {
            int c = wid * 2 + p;
            int r = c * 16 + (lane >> 2);
            int ac = (lane & 3) * 8;
#pragma unroll
            for (int pnl = 0; pnl < 2; pnl++) {
                int cc = k0 + pnl * 32 + ac;
                gload_lds16(A  + (long)(rowbase + r) * DIM + cc,
                            &smem[pnl * 4096 + c * 16 * 32]);
                gload_lds16(Bt + (long)(colbase + r) * DIM + cc,
                            &smem[8192 + pnl * 4096 + c * 16 * 32]);
            }
        }
        __syncthreads();
#pragma unroll
        for (int pnl = 0; pnl < 2; pnl++) {
            bf16x8 fa[4], fb[4];
#pragma unroll
            for (int t = 0; t < 4; t++)
                fa[t] = *(const bf16x8*)(&smem[pnl * 4096 + (wm * 64 + t * 16 + l16) * 32 + quad * 8]);
#pragma unroll
            for (int t = 0; t < 4; t++)
                fb[t] = *(const bf16x8*)(&smem[8192 + pnl * 4096 + (wn * 64 + t * 16 + l16) * 32 + quad * 8]);
#pragma unroll
            for (int i = 0; i < 4; i++)
#pragma unroll
                for (int j = 0; j < 4; j++)
                    acc[i][j] = __builtin_amdgcn_mfma_f32_16x16x32_bf16(fa[i], fb[j], acc[i][j], 0, 0, 0);
        }
        __syncthreads();
    }

    if (colbase >= 2048) {
        // V block: acc -> T[col_local][row_local] (stride 136) -> V^T write
#pragma unroll
        for (int i = 0; i < 4; i++)
#pragma unroll
            for (int j = 0; j < 4; j++) {
                int cl = wn * 64 + j * 16 + l16;
                int rl = wm * 64 + i * 16 + quad * 4;
#pragma unroll
                for (int r = 0; r < 4; r++)
                    smem[cl * 136 + rl + r] = f2b(acc[i][j][r]);
            }
        __syncthreads();
        int b = rowbase >> 11, nnb = rowbase & 2047;
        int hbase = (colbase - 2048) >> 6;
#pragma unroll
        for (int i = 0; i < 8; i++) {
            int id = i * 256 + tid;           // 0..2047
            int cl = id >> 4;                 // local col 0..127
            int off = (id & 15) * 8;          // 0..120
            int hh = hbase + (cl >> 6), d = cl & 63;
            uint4 val = *(const uint4*)(&smem[cl * 136 + off]);
            *(uint4*)(vp + (((long)b * HEADS + hh) * HDIM + d) * SEQ + nnb + off) = val;
        }
    } else {
        // q/k block: acc -> T[row_local][col_local] (stride 136, q pre-scaled)
        // -> coalesced uint4 row writes (8 contiguous d per thread)
        float s = (colbase < 1024) ? 0.18033688011f : 1.0f;  // 1/8 * log2(e)
#pragma unroll
        for (int i = 0; i < 4; i++)
#pragma unroll
            for (int j = 0; j < 4; j++) {
                int rl = wm * 64 + i * 16 + quad * 4;
                int cl = wn * 64 + j * 16 + l16;
#pragma unroll
                for (int r = 0; r < 4; r++)
                    smem[(rl + r) * 136 + cl] = f2b(acc[i][j][r] * s);
            }
        __syncthreads();
        ushort* dst = (colbase < 1024) ? qp : kp;
        int cb = colbase & 1023;
#pragma unroll
        for (int i = 0; i < 8; i++) {
            int id = i * 256 + tid;           // 0..2047
            int rl = id >> 4;                 // local row 0..127
            int ch = id & 15;                 // 8-col chunk
            int col = cb + ch * 8;
            int head = col >> 6, d = col & 63;
            int mm = rowbase + rl;
            int b = mm >> 11, nn = mm & 2047;
            uint4 val = *(const uint4*)(&smem[rl * 136 + ch * 8]);
            *(uint4*)(dst + ((((long)b * HEADS + head) * SEQ + nn) << 6) + d) = val;
        }
    }
}

// ------- Proj GEMM: 128x64 tile, BK=64; grid 512 -----------------------------
__global__ __launch_bounds__(256, 3)
void gemm_proj_k(const ushort* __restrict__ A, const ushort* __restrict__ Bt,
                 const float* __restrict__ bias, const float* __restrict__ xres,
                 float* __restrict__ outp) {
    __shared__ ushort As[2][128][32];   // 16 KB
    __shared__ ushort Bs[2][64][32];    // 8 KB
    int tid  = threadIdx.x;
    int wid  = tid >> 6, lane = tid & 63;
    int quad = lane >> 4, l16 = lane & 15;
    int rowbase = blockIdx.y * 128;
    int colbase = blockIdx.x * 64;
    int arow = lane >> 2, acol = (lane & 3) * 8;

    f32x4 acc[2][4];
#pragma unroll
    for (int i = 0; i < 2; i++)
#pragma unroll
        for (int j = 0; j < 4; j++) acc[i][j] = (f32x4){0.f, 0.f, 0.f, 0.f};

    for (int k0 = 0; k0 < DIM; k0 += 64) {
#pragma unroll
        for (int p = 0; p < 2; p++) {
            int c = wid * 2 + p;
            int r = c * 16 + arow;
            int mm = rowbase + r;
            int bq = mm >> 11, nn = mm & 2047;
#pragma unroll
            for (int pnl = 0; pnl < 2; pnl++) {
                int cc = k0 + pnl * 32 + acol;
                int head = cc >> 6, d = cc & 63;
                gload_lds16(A + ((((long)bq * HEADS + head) * SEQ + nn) << 6) + d,
                            &As[pnl][c * 16][0]);
            }
        }
        {
            int r = wid * 16 + arow;
#pragma unroll
            for (int pnl = 0; pnl < 2; pnl++) {
                int cc = k0 + pnl * 32 + acol;
                gload_lds16(Bt + (long)(colbase + r) * DIM + cc, &Bs[pnl][wid * 16][0]);
            }
        }
        __syncthreads();
#pragma unroll
        for (int pnl = 0; pnl < 2; pnl++) {
            bf16x8 fa[2], fb[4];
#pragma unroll
            for (int t = 0; t < 2; t++)
                fa[t] = *(const bf16x8*)(&As[pnl][wid * 32 + t * 16 + l16][quad * 8]);
#pragma unroll
            for (int t = 0; t < 4; t++)
                fb[t] = *(const bf16x8*)(&Bs[pnl][t * 16 + l16][quad * 8]);
#pragma unroll
            for (int i = 0; i < 2; i++)
#pragma unroll
                for (int j = 0; j < 4; j++)
                    acc[i][j] = __builtin_amdgcn_mfma_f32_16x16x32_bf16(fa[i], fb[j], acc[i][j], 0, 0, 0);
        }
        __syncthreads();
    }

#pragma unroll
    for (int i = 0; i < 2; i++)
#pragma unroll
        for (int j = 0; j < 4; j++) {
            int m0  = rowbase + wid * 32 + i * 16 + quad * 4;
            int col = colbase + j * 16 + l16;
#pragma unroll
            for (int r = 0; r < 4; r++) {
                int mm = m0 + r;
                outp[(long)mm * DIM + col] = acc[i][j][r] + bias[col] + xres[(long)mm * DIM + col];
            }
        }
}

// ------- flash attention: KVBLK=64, 32x32 MFMA, in-register softmax ----------
// r2 structure (best measured: 47.8 us). XCD-chunked block swizzle (T1):
// 512 blocks = 8 XCDs x 64; each XCD owns 4 consecutive bh -> 2 MB KV
// working set, L2-resident across its 16 q-tiles.
// Both K and V LDS tiles are [64 rows][64 cols] (row stride = 128 B = full
// bank width), 16B-slot swizzle: physical_slot = logical_slot ^ (row & 7).
// Swapped QK^T: C[key][q], col=q=lane&31, row=key=(reg&3)+8*(reg>>2)+4*hi.
__global__ __launch_bounds__(256, 2)
void attn_k(ushort* qio, const ushort* __restrict__ kg,
            const ushort* __restrict__ vt) {
    __shared__ __align__(16) ushort Kp[2][4096];   // 16 KB: [buf] 64 key x 64 d
    __shared__ __align__(16) ushort Vs[2][4096];   // 16 KB: [buf] 64 d x 64 k
    int flat = blockIdx.x;                    // 0..511
    int swz  = (flat & 7) * 64 + (flat >> 3); // bijective: XCD c -> bh [4c,4c+4)
    int qx = swz & 15, bh = swz >> 4;
    int tid = threadIdx.x, wid = tid >> 6;
    int lane = tid & 63;
    int l31 = lane & 31, hi = lane >> 5;
    ushort* qh = qio + (long)bh * SEQ * HDIM;
    const ushort* kh = kg + (long)bh * SEQ * HDIM;
    const ushort* vh = vt + (long)bh * HDIM * SEQ;

    // staging: 256 threads x 2 shots x 16B for each of K and V.
    // shot s: row = (tid>>3)+32*s, chunk = tid&7  -> fully coalesced 128B rows.
    int srow = tid >> 3, schk = tid & 7;
    int sofs = srow * 64 + ((schk ^ (srow & 7)) * 8);   // shot1 ofs = sofs+2048
    const ushort* kbase = kh + (long)srow * HDIM + schk * 8;
    const ushort* vbase = vh + (long)srow * SEQ + schk * 8;

    int qrow0 = qx * 128 + wid * 32;
    // Q B-frag: lane holds Q[q=l31][d = ks*16 + hi*8 + j]
    bf16x8 qf[4];
#pragma unroll
    for (int ks = 0; ks < 4; ks++)
        qf[ks] = *(const bf16x8*)(qh + (long)(qrow0 + l31) * HDIM + ks * 16 + hi * 8);

    f32x16 o0 = {}, o1 = {};                // PV acc: col=d=l31(+32)
    f32x4 lac = {0.f, 0.f, 0.f, 0.f};       // per-column (q) exp sums

    uint4 kr0 = *(const uint4*)(kbase);
    uint4 kr1 = *(const uint4*)(kbase + 32 * HDIM);
    uint4 vr0 = *(const uint4*)(vbase);
    uint4 vr1 = *(const uint4*)(vbase + 32 * SEQ);
    *(uint4*)(&Kp[0][sofs])        = kr0;
    *(uint4*)(&Kp[0][sofs + 2048]) = kr1;   // (srow+32)&7 == srow&7
    *(uint4*)(&Vs[0][sofs])        = vr0;
    *(uint4*)(&Vs[0][sofs + 2048]) = vr1;

    const int NIT = SEQ / 64;   // 32
    for (int it = 0; it < NIT; ++it) {
        int buf = it & 1;
        if (it + 1 < NIT) {
            int kt = (it + 1) * 64;
            kr0 = *(const uint4*)(kbase + (long)kt * HDIM);
            kr1 = *(const uint4*)(kbase + (long)(kt + 32) * HDIM);
            vr0 = *(const uint4*)(vbase + kt);
            vr1 = *(const uint4*)(vbase + 32 * SEQ + kt);
        }
        __syncthreads();

        // QK^T: A = K[key][d], B = Q^T[d][q]; two independent 4-chains
        f32x16 sc0 = {}, sc1 = {};
        __builtin_amdgcn_s_setprio(1);
#pragma unroll
        for (int ks = 0; ks < 4; ks++) {
            int psl = ((2 * ks + hi) ^ (l31 & 7)) * 8;
            bf16x8 ka = *(const bf16x8*)(&Kp[buf][l31 * 64 + psl]);
            bf16x8 kb = *(const bf16x8*)(&Kp[buf][(32 + l31) * 64 + psl]);
            sc0 = __builtin_amdgcn_mfma_f32_32x32x16_bf16(ka, qf[ks], sc0, 0, 0, 0);
            sc1 = __builtin_amdgcn_mfma_f32_32x32x16_bf16(kb, qf[ks], sc1, 0, 0, 0);
        }
        __builtin_amdgcn_s_setprio(0);

        // softmax numerators: 2^(sc) (log2e folded into q scale)
        float e0[16], e1[16];
#pragma unroll
        for (int r = 0; r < 16; r++) { e0[r] = fexp2(sc0[r]); e1[r] = fexp2(sc1[r]); }
#pragma unroll
        for (int r = 0; r < 4; r++)
            lac += (f32x4){e0[4*r], e0[4*r+1], e0[4*r+2], e0[4*r+3]}
                 + (f32x4){e1[4*r], e1[4*r+1], e1[4*r+2], e1[4*r+3]};

        // P -> A-frags: 4 groups of 16 keys
        bf16x8 pa0 = pack8(e0[0], e0[1], e0[2],  e0[3],  e0[4],  e0[5],  e0[6],  e0[7]);
        bf16x8 pa1 = pack8(e0[8], e0[9], e0[10], e0[11], e0[12], e0[13], e0[14], e0[15]);
        bf16x8 pa2 = pack8(e1[0], e1[1], e1[2],  e1[3],  e1[4],  e1[5],  e1[6],  e1[7]);
        bf16x8 pa3 = pack8(e1[8], e1[9], e1[10], e1[11], e1[12], e1[13], e1[14], e1[15]);

        // PV: A = P[q][k], B = V[k][d] column slices; two independent 4-chains
        __builtin_amdgcn_s_setprio(1);
#pragma unroll
        for (int g = 0; g < 4; g++) {
            int psl = ((2 * g + hi) ^ (l31 & 7)) * 8;
            bf16x8 v0 = *(const bf16x8*)(&Vs[buf][l31 * 64 + psl]);
            bf16x8 v1 = *(const bf16x8*)(&Vs[buf][(32 + l31) * 64 + psl]);
            bf16x8 pg = (g == 0) ? pa0 : (g == 1) ? pa1 : (g == 2) ? pa2 : pa3;
            o0 = __builtin_amdgcn_mfma_f32_32x32x16_bf16(pg, v0, o0, 0, 0, 0);
            o1 = __builtin_amdgcn_mfma_f32_32x32x16_bf16(pg, v1, o1, 0, 0, 0);
        }
        __builtin_amdgcn_s_setprio(0);

        if (it + 1 < NIT) {
            *(uint4*)(&Kp[buf ^ 1][sofs])        = kr0;
            *(uint4*)(&Kp[buf ^ 1][sofs + 2048]) = kr1;
            *(uint4*)(&Vs[buf ^ 1][sofs])        = vr0;
            *(uint4*)(&Vs[buf ^ 1][sofs + 2048]) = vr1;
        }
    }

    // denominators: column q sums split across lane pair (q, q+32)
    float t = lac[0] + lac[1] + lac[2] + lac[3];
    t += __shfl_xor(t, 32);
    float linv = 1.0f / t;          // valid in lanes q and q+32 for column q=l31
#pragma unroll
    for (int r = 0; r < 16; r++) {
        int qrow = (r & 3) + 8 * (r >> 2) + 4 * hi;
        float lr = __shfl(linv, qrow);        // lane qrow holds 1/sum for q=qrow
        long ro = (long)(qrow0 + qrow) * HDIM;
        qh[ro + l31]      = f2b(o0[r] * lr);
        qh[ro + 32 + l31] = f2b(o1[r] * lr);
    }
}

// ------- launch --------------------------------------------------------------
extern "C" void kernel_launch(void* const* d_in, const int* in_sizes, int n_in,
                              void* d_out, int out_size, void* d_ws, size_t ws_size,
                              hipStream_t stream) {
    const float* x      = (const float*)d_in[0];
    const float* w_qkv  = (const float*)d_in[1];
    const float* w_proj = (const float*)d_in[2];
    const float* b_proj = (const float*)d_in[3];
    const float* gamma  = (const float*)d_in[4];
    const float* beta   = (const float*)d_in[5];
    float* out = (float*)d_out;

    // workspace: 19M bf16 elements = 38 MB
    ushort* ws   = (ushort*)d_ws;
    ushort* h    = ws;                      // 4M: LN output
    ushort* wqt  = ws + (size_t)4 * MEG;    // 3M: w_qkv^T (bf16)
    ushort* qb   = ws + (size_t)7 * MEG;    // 4M: q (pre-scaled), then attn out (q-layout)
    ushort* kb   = ws + (size_t)11 * MEG;   // 4M: k, then w_proj^T
    ushort* vtb  = ws + (size_t)15 * MEG;   // 4M: V^T [B,H][D][N] (written by QKV epilogue)

    // 1) transpose+cast w_qkv f32[K][3N] -> bf16 [3N][K]
    transpose_f2b_k<<<dim3(3 * DIM / 32, DIM / 32), dim3(32, 8), 0, stream>>>(
        w_qkv, wqt, DIM, 3 * DIM);
    // 2) layernorm f32 -> bf16 h
    ln_k<<<dim3(TOK), dim3(256), 0, stream>>>(x, gamma, beta, h);
    // 3) qkv gemm: scatter q/k, V^T written directly (fused transpose)
    gemm_qkv_k<<<dim3(3 * DIM / 128, TOK / 128), dim3(256), 0, stream>>>(
        h, wqt, qb, kb, vtb);
    // 4) flash attention; output overwrites q buffer in q-layout
    attn_k<<<dim3((SEQ / 128) * BATCH * HEADS), dim3(256), 0, stream>>>(qb, kb, vtb);
    // 5) transpose+cast w_proj into dead k slot
    transpose_f2b_k<<<dim3(DIM / 32, DIM / 32), dim3(32, 8), 0, stream>>>(
        w_proj, kb, DIM, DIM);
    // 6) proj gemm (+fp32 bias +fp32 residual) -> fp32 out, 128x64 tiles
    gemm_proj_k<<<dim3(DIM / 64, TOK / 128), dim3(256), 0, stream>>>(
        qb, kb, b_proj, x, out);
}